// Round 1
// 11925.661 us; speedup vs baseline: 2.0716x; 2.0716x over previous
//
#include <hip/hip_runtime.h>
#include <math.h>

// Problem dims (fixed)
#define Bh   64
#define LXh  64
#define LYh  64
#define Dh   512
#define NEh  512
#define E2h  1024
#define Hh   8
#define G3h  1536
#define TPB  512      // 8 waves per WG
#define NWG  256      // 64 groups x 4 WGs, 1 WG per CU

// ---------------------------------------------------------------------------
// Cross-WG data moves via agent-scope relaxed atomics: these bypass the
// per-XCD L2s (coherence point), so no stale-L2 hazard. Ordering comes from
// the group barrier: __syncthreads() drains vmcnt before the arrive-add.
// ---------------------------------------------------------------------------
__device__ __forceinline__ float g_ld(const float* p) {
    return __hip_atomic_load((const float*)p, __ATOMIC_RELAXED, __HIP_MEMORY_SCOPE_AGENT);
}
__device__ __forceinline__ void g_st(float* p, float v) {
    __hip_atomic_store(p, v, __ATOMIC_RELAXED, __HIP_MEMORY_SCOPE_AGENT);
}
__device__ __forceinline__ float sigm(float x) { return 1.f / (1.f + expf(-x)); }

// GEMV single column: sum_k x[k] * W[k*ldw + col].  W reads are coalesced
// across consecutive threads (consecutive cols); x lives in LDS (broadcast).
// Unroll 16 keeps 16 global loads in flight per wave for latency hiding.
__device__ __forceinline__ float gemv_col(const float* __restrict__ W, int ldw,
                                          int col, const float* __restrict__ x, int K)
{
    const float* wp = W + col;
    float acc = 0.f;
    for (int k = 0; k < K; k += 16) {
        float w[16];
        #pragma unroll
        for (int u = 0; u < 16; ++u) w[u] = wp[(size_t)(k + u) * ldw];
        #pragma unroll
        for (int u = 0; u < 16; ++u) acc = fmaf(x[k + u], w[u], acc);
    }
    return acc;
}

__global__ __launch_bounds__(TPB) void decoder_persistent(
    const float* __restrict__ xs_h, const float* __restrict__ ys_e,
    const float* __restrict__ xs_mask, const float* __restrict__ ys_mask,
    const float* __restrict__ W_sinit, const float* __restrict__ b_sinit,
    const float* __restrict__ W_keys,
    const float* __restrict__ Wx_cell, const float* __restrict__ bx_cell,
    const float* __restrict__ gx_cell, const float* __restrict__ Wh_cell,
    const float* __restrict__ gh_cell,
    const float* __restrict__ Wx_cond, const float* __restrict__ bx_cond,
    const float* __restrict__ gx_cond, const float* __restrict__ Wh_cond,
    const float* __restrict__ gh_cond,
    const float* __restrict__ Wq, const float* __restrict__ bq,
    const float* __restrict__ V_att, const float* __restrict__ Wo,
    const float* __restrict__ bo, const float* __restrict__ Wy,
    const float* __restrict__ by, const float* __restrict__ Wc,
    const float* __restrict__ bc, const float* __restrict__ Wsm,
    const float* __restrict__ bs,
    float* __restrict__ out, float* __restrict__ ws)
{
    const int w   = blockIdx.x;
    const int tid = threadIdx.x;
    // XCD-aligned mapping: blockIdx%8 ~ XCD; WGs with same slice i land on a
    // fixed XCD pair so each XCD's L2 caches (mostly) one 5.2MB weight slice.
    const int i = (w & 7) >> 1;                 // column-slice 0..3
    const int b = ((w >> 3) << 1) | (w & 1);    // batch row 0..63

    // ---- workspace layout (floats) ----
    unsigned* cnt = ((unsigned*)ws) + (size_t)b * 16;   // 64B-padded counter per group
    float* AXn  = ws + 1024;                              // [64][64][1536] LN'd x-branch
    float* YWbP = AXn  + (size_t)Bh * LYh * G3h;          // [256wg][64][128] private
    float* uhP  = YWbP + (size_t)NWG * LYh * 128;         // [256wg][16][512] private
    float* PB   = uhP  + (size_t)NWG * 16 * Dh;           // per-b shared block
    float* pb    = PB + (size_t)b * 8704;
    float* tmpH  = pb;            // 1536
    float* tmpHC = pb + 1536;     // 1536
    float* tmpXC = pb + 3072;     // 1536
    float* qb_   = pb + 4608;     // 512
    float* e_    = pb + 5120;     // 64*8
    float* ctx0_ = pb + 5632;     // 1024
    float* ctx_  = pb + 6656;     // 1024
    float* pool_ = pb + 7680;     // 1024

    __shared__ float xv[1024];    // staged x-vector
    __shared__ float sbl[512];    // "state" (cell-GRU out), identical in all 4 WGs
    __shared__ float sal[512];    // carry s_t, identical in all 4 WGs
    __shared__ float el[512];     // e scores staged
    __shared__ float al[512];     // alpha
    __shared__ float comb[512];   // K-split partials
    __shared__ float outcl[128];  // ctx@Wc slice
    __shared__ float red[8][12];  // block-reduce scratch
    __shared__ float xml[64];     // xs_mask row

    unsigned gen = 0;
    auto gbar = [&]() {
        __syncthreads();                      // drains vmcnt(0): release for all stores
        ++gen;
        if (tid == 0) {
            __hip_atomic_fetch_add(cnt, 1u, __ATOMIC_RELAXED, __HIP_MEMORY_SCOPE_AGENT);
            while (__hip_atomic_load(cnt, __ATOMIC_RELAXED, __HIP_MEMORY_SCOPE_AGENT) < 4u * gen)
                __builtin_amdgcn_s_sleep(4);
        }
        asm volatile("" ::: "memory");
        __syncthreads();
    };

    auto block_reduce = [&](float* v, int nv) {   // sum over 512 threads, broadcast
        for (int n = 0; n < nv; ++n) {
            float x = v[n];
            #pragma unroll
            for (int off = 32; off; off >>= 1) x += __shfl_xor(x, off);
            v[n] = x;
        }
        int wv = tid >> 6, ln = tid & 63;
        if (ln == 0) for (int n = 0; n < nv; ++n) red[wv][n] = v[n];
        __syncthreads();
        for (int n = 0; n < nv; ++n) {
            float s = 0.f;
            for (int wq = 0; wq < 8; ++wq) s += red[wq][n];
            v[n] = s;
        }
        __syncthreads();
    };

    // ======================= precompute (once) =======================
    if (tid < 64) xml[tid] = xs_mask[(size_t)b * LXh + tid];
    float vatt[8];
    #pragma unroll
    for (int h = 0; h < 8; ++h) vatt[h] = V_att[(size_t)tid * Hh + h];
    __syncthreads();

    // uh rows for my 16 l's (private):  uh[l,d] = xs_h[b,l,:] @ W_keys
    for (int li = 0; li < 16; ++li) {
        int l = i * 16 + li;
        for (int k = tid; k < E2h; k += TPB) xv[k] = xs_h[((size_t)b * LXh + l) * E2h + k];
        __syncthreads();
        uhP[((size_t)w * 16 + li) * Dh + tid] = gemv_col(W_keys, Dh, tid, xv, E2h);
        __syncthreads();
    }

    // AXn rows for my 16 t's: LN(ys_e@Wx_cell)*gx+bx, published
    for (int ti = 0; ti < 16; ++ti) {
        int t = i * 16 + ti;
        for (int k = tid; k < NEh; k += TPB) xv[k] = ys_e[((size_t)b * LYh + t) * NEh + k];
        __syncthreads();
        float raw[3], st[6];
        #pragma unroll
        for (int g = 0; g < 3; ++g) {
            raw[g] = gemv_col(Wx_cell, G3h, g * Dh + tid, xv, NEh);
            st[2 * g] = raw[g]; st[2 * g + 1] = raw[g] * raw[g];
        }
        block_reduce(st, 6);
        #pragma unroll
        for (int g = 0; g < 3; ++g) {
            float mu   = st[2 * g] * (1.f / 512.f);
            float var  = st[2 * g + 1] * (1.f / 512.f) - mu * mu;
            float rstd = rsqrtf(var + 1e-5f);
            int c = g * Dh + tid;
            g_st(&AXn[((size_t)b * LYh + t) * G3h + c],
                 (raw[g] - mu) * rstd * gx_cell[c] + bx_cell[c]);
        }
        __syncthreads();
    }

    // YWb slice for all t (private): ys_e@Wy + by, cols [i*128, i*128+128)
    for (int t = 0; t < LYh; ++t) {
        for (int k = tid; k < NEh; k += TPB) xv[k] = ys_e[((size_t)b * LYh + t) * NEh + k];
        __syncthreads();
        { int c = tid & 127, q = tid >> 7;
          comb[tid] = gemv_col(Wy + (size_t)q * 128 * Dh, Dh, i * 128 + c, xv + q * 128, 128); }
        __syncthreads();
        if (tid < 128) {
            YWbP[((size_t)w * LYh + t) * 128 + tid] =
                comb[tid] + comb[128 + tid] + comb[256 + tid] + comb[384 + tid] + by[i * 128 + tid];
        }
        __syncthreads();
    }

    // pooled slice (cols [i*256, i*256+256))
    {
        float msum = 0.f;
        for (int l = 0; l < LXh; ++l) msum += xml[l];
        if (tid < 256) {
            float a = 0.f;
            for (int l = 0; l < LXh; ++l)
                a += __builtin_nontemporal_load(&xs_h[((size_t)b * LXh + l) * E2h + i * 256 + tid]) * xml[l];
            g_st(&pool_[i * 256 + tid], a / msum);
        }
    }
    gbar();   // publish AXn + pooled

    // s0 = tanh(pooled @ W_sinit + b) — computed redundantly (identical) per WG
    for (int k = tid; k < E2h; k += TPB) xv[k] = g_ld(&pool_[k]);
    __syncthreads();
    sal[tid] = tanhf(gemv_col(W_sinit, Dh, tid, xv, E2h) + b_sinit[tid]);
    __syncthreads();
    // P1(t=0): tmpH slice = sA @ Wh_cell
    if (tid < 384) g_st(&tmpH[i * 384 + tid], gemv_col(Wh_cell, G3h, i * 384 + tid, sal, Dh));
    gbar();

    // ======================= sequential scan =======================
    for (int t = 0; t < LYh; ++t) {
        const float ym = ys_mask[(size_t)b * LYh + t];

        // ---- phase A: cell-GRU (redundant, full) then qb/tmpHC GEMV ----
        {
            float th[3], ax[3], st[6];
            #pragma unroll
            for (int g = 0; g < 3; ++g) {
                th[g] = g_ld(&tmpH[g * Dh + tid]);
                ax[g] = g_ld(&AXn[((size_t)b * LYh + t) * G3h + g * Dh + tid]);
                st[2 * g] = th[g]; st[2 * g + 1] = th[g] * th[g];
            }
            block_reduce(st, 6);
            float ah[3];
            #pragma unroll
            for (int g = 0; g < 3; ++g) {
                float mu   = st[2 * g] * (1.f / 512.f);
                float var  = st[2 * g + 1] * (1.f / 512.f) - mu * mu;
                ah[g] = (th[g] - mu) * rsqrtf(var + 1e-5f) * gh_cell[g * Dh + tid];
            }
            float h  = sal[tid];
            float r  = sigm(ax[0] + ah[0]);
            float z  = sigm(ax[1] + ah[1]);
            float hc = tanhf(ax[2] + r * ah[2]);
            float hn = (1.f - z) * h + z * hc;
            sbl[tid] = ym * hn + (1.f - ym) * h;
        }
        __syncthreads();
        if (tid < 128) { int c = i * 128 + tid;
            g_st(&qb_[c], gemv_col(Wq, Dh, c, sbl, Dh) + bq[c]);
        } else { int c = i * 384 + (tid - 128);
            g_st(&tmpHC[c], gemv_col(Wh_cond, G3h, c, sbl, Dh));
        }
        gbar();  // A

        // ---- phase B: additive attention scores for my 16 l's ----
        for (int k = tid; k < Dh; k += TPB) xv[k] = g_ld(&qb_[k]);
        __syncthreads();
        for (int li = 0; li < 16; ++li) {
            int l = i * 16 + li;
            float hid = tanhf(uhP[((size_t)w * 16 + li) * Dh + tid] + xv[tid]);
            float p[8];
            #pragma unroll
            for (int h = 0; h < 8; ++h) p[h] = hid * vatt[h];
            block_reduce(p, 8);
            if (tid < 8) g_st(&e_[l * Hh + tid], (xml[l] > 0.f) ? p[tid] : -1e9f);
        }
        gbar();  // B

        // ---- phase C: softmax over l (redundant) + ctx0 slice ----
        for (int k = tid; k < 512; k += TPB) el[k] = g_ld(&e_[k]);
        __syncthreads();
        {   // wave wv handles head wv; lane = l
            int wv = tid >> 6, l = tid & 63;
            float v = el[l * Hh + wv];
            float mx = v;
            #pragma unroll
            for (int off = 32; off; off >>= 1) mx = fmaxf(mx, __shfl_xor(mx, off));
            float ex = expf(v - mx);
            float ssum = ex;
            #pragma unroll
            for (int off = 32; off; off >>= 1) ssum += __shfl_xor(ssum, off);
            al[l * Hh + wv] = ex / ssum;
        }
        __syncthreads();
        if (tid < 256) {
            int h8 = (i * 256 + tid) >> 7;
            float a = 0.f;
            for (int l = 0; l < LXh; ++l)
                a += al[l * Hh + h8] *
                     __builtin_nontemporal_load(&xs_h[((size_t)b * LXh + l) * E2h + i * 256 + tid]);
            g_st(&ctx0_[i * 256 + tid], a);
        }
        gbar();  // C

        // ---- phase D: ctx = (ctx0 @ Wo + bo) * ym  (K=1024 split-2) ----
        for (int k = tid; k < E2h; k += TPB) xv[k] = g_ld(&ctx0_[k]);
        __syncthreads();
        { int c = i * 256 + (tid & 255), q = tid >> 8;
          comb[tid] = gemv_col(Wo + (size_t)q * 512 * E2h, E2h, c, xv + q * 512, 512); }
        __syncthreads();
        if (tid < 256) { int c = i * 256 + tid;
            g_st(&ctx_[c], (comb[tid] + comb[256 + tid] + bo[c]) * ym); }
        gbar();  // D

        // ---- phase E: tmpXC slice (384) + outc slice (128), K=1024 ----
        for (int k = tid; k < E2h; k += TPB) xv[k] = g_ld(&ctx_[k]);
        __syncthreads();
        if (tid < 384) { int c = i * 384 + tid;
            g_st(&tmpXC[c], gemv_col(Wx_cond, G3h, c, xv, E2h));
        } else { int j = tid - 384;
            outcl[j] = gemv_col(Wc, Dh, i * 128 + j, xv, E2h);
        }
        gbar();  // E

        // ---- phase F: cond-GRU (redundant) + out + P1(t+1) ----
        {
            float tx[3], thc[3], st[12];
            #pragma unroll
            for (int g = 0; g < 3; ++g) {
                tx[g]  = g_ld(&tmpXC[g * Dh + tid]);
                thc[g] = g_ld(&tmpHC[g * Dh + tid]);
                st[4 * g + 0] = tx[g];  st[4 * g + 1] = tx[g] * tx[g];
                st[4 * g + 2] = thc[g]; st[4 * g + 3] = thc[g] * thc[g];
            }
            block_reduce(st, 12);
            float axc[3], ahc[3];
            #pragma unroll
            for (int g = 0; g < 3; ++g) {
                int c = g * Dh + tid;
                float mu   = st[4 * g + 0] * (1.f / 512.f);
                float var  = st[4 * g + 1] * (1.f / 512.f) - mu * mu;
                axc[g] = (tx[g] - mu) * rsqrtf(var + 1e-5f) * gx_cond[c] + bx_cond[c];
                float muh  = st[4 * g + 2] * (1.f / 512.f);
                float varh = st[4 * g + 3] * (1.f / 512.f) - muh * muh;
                ahc[g] = (thc[g] - muh) * rsqrtf(varh + 1e-5f) * gh_cond[c];
            }
            float h  = sbl[tid];
            float r  = sigm(axc[0] + ahc[0]);
            float z  = sigm(axc[1] + ahc[1]);
            float hc = tanhf(axc[2] + r * ahc[2]);
            float hn = (1.f - z) * h + z * hc;
            float snew = ym * hn + (1.f - ym) * h;
            __syncthreads();
            sal[tid] = snew;
        }
        __syncthreads();
        // out slice: tanh(YWb + ctx@Wc + sA@Ws + bc + bs) * ym   (K=512 split-4)
        { int c = tid & 127, q = tid >> 7;
          comb[tid] = gemv_col(Wsm + (size_t)q * 128 * Dh, Dh, i * 128 + c, sal + q * 128, 128); }
        __syncthreads();
        if (tid < 128) {
            int c = i * 128 + tid;
            float v = comb[tid] + comb[128 + tid] + comb[256 + tid] + comb[384 + tid]
                    + YWbP[((size_t)w * LYh + t) * 128 + tid] + outcl[tid]
                    + bc[c] + bs[c];
            out[((size_t)b * LYh + t) * Dh + c] = tanhf(v) * ym;
        }
        // P1 for next step: tmpH slice = sA_new @ Wh_cell
        if (t + 1 < LYh && tid < 384) { int c = i * 384 + tid;
            g_st(&tmpH[c], gemv_col(Wh_cell, G3h, c, sal, Dh)); }
        gbar();  // F
    }
}

// ---------------------------------------------------------------------------
extern "C" void kernel_launch(void* const* d_in, const int* in_sizes, int n_in,
                              void* d_out, int out_size, void* d_ws, size_t ws_size,
                              hipStream_t stream)
{
    // zero the 64 padded group-barrier counters (re-zeroed on every graph replay)
    hipMemsetAsync(d_ws, 0, 4096, stream);

    decoder_persistent<<<dim3(NWG), dim3(TPB), 0, stream>>>(
        (const float*)d_in[0],  (const float*)d_in[1],  (const float*)d_in[2],
        (const float*)d_in[3],  (const float*)d_in[4],  (const float*)d_in[5],
        (const float*)d_in[6],  (const float*)d_in[7],  (const float*)d_in[8],
        (const float*)d_in[9],  (const float*)d_in[10], (const float*)d_in[11],
        (const float*)d_in[12], (const float*)d_in[13], (const float*)d_in[14],
        (const float*)d_in[15], (const float*)d_in[16], (const float*)d_in[17],
        (const float*)d_in[18], (const float*)d_in[19], (const float*)d_in[20],
        (const float*)d_in[21], (const float*)d_in[22], (const float*)d_in[23],
        (const float*)d_in[24], (const float*)d_in[25], (const float*)d_in[26],
        (const float*)d_in[27],
        (float*)d_out, (float*)d_ws);
}

// Round 4
// 5026.565 us; speedup vs baseline: 4.9149x; 2.3725x over previous
//
#include <hip/hip_runtime.h>
#include <math.h>

#define TPB 512
#define NWG 256   // 32 groups x 8 WGs, 1 WG/CU

// Cross-WG traffic: agent-scope relaxed atomics (coherence point, no stale-L2).
// Ordering: gbar's __syncthreads drains vmcnt before the arrive-add.
// ALL cross-WG data goes through g_ld/g_st; weight matrices are read-only
// kernel inputs (plain cached reads are safe and L2-resident by design).
__device__ __forceinline__ float g_ld(const float* p){
    return __hip_atomic_load(p, __ATOMIC_RELAXED, __HIP_MEMORY_SCOPE_AGENT);
}
__device__ __forceinline__ void g_st(float* p, float v){
    __hip_atomic_store(p, v, __ATOMIC_RELAXED, __HIP_MEMORY_SCOPE_AGENT);
}
__device__ __forceinline__ float sigm(float x){ return 1.f/(1.f+expf(-x)); }

__global__ __launch_bounds__(TPB) void decoder_persistent(
    const float* __restrict__ xs_h, const float* __restrict__ ys_e,
    const float* __restrict__ xs_mask, const float* __restrict__ ys_mask,
    const float* __restrict__ W_sinit, const float* __restrict__ b_sinit,
    const float* __restrict__ W_keys,
    const float* __restrict__ Wx_cell, const float* __restrict__ bx_cell,
    const float* __restrict__ gx_cell, const float* __restrict__ Wh_cell,
    const float* __restrict__ gh_cell,
    const float* __restrict__ Wx_cond, const float* __restrict__ bx_cond,
    const float* __restrict__ gx_cond, const float* __restrict__ Wh_cond,
    const float* __restrict__ gh_cond,
    const float* __restrict__ Wq, const float* __restrict__ bq,
    const float* __restrict__ V_att, const float* __restrict__ Wo,
    const float* __restrict__ bo, const float* __restrict__ Wy,
    const float* __restrict__ by, const float* __restrict__ Wc,
    const float* __restrict__ bc, const float* __restrict__ Wsm,
    const float* __restrict__ bs,
    float* __restrict__ out, float* __restrict__ ws)
{
    const int w    = blockIdx.x;
    const int tid  = threadIdx.x;
    const int lane = tid & 63, wv = tid >> 6;
    const int i    = w & 7;          // column slice (== XCD under %8 mapping; perf-only)
    const int grp  = w >> 3;         // group 0..31
    const int b0   = grp * 2;        // this group's 2 batch rows

    // ---------------- workspace layout (floats), total ~11.08M = 44.3 MB ----------------
    unsigned* cntg = (unsigned*)ws + (size_t)grp * 16;   // group barrier ctr (64B padded)
    float* AXn  = ws + 1024;                             // [64][64][1536] LN'd x-branch
    float* uhP  = AXn  + (size_t)64*64*1536;             // [256][16][512] WG-private
    float* YWbP = uhP  + (size_t)256*16*512;             // [256][2][64][64] WG-private
    float* PB   = YWbP + (size_t)256*2*64*64;            // [32][18432] per-group block
    float* pb     = PB + (size_t)grp * 18432;
    float* tmpH_  = pb;            // [2][1536]
    float* tmpHC_ = pb + 3072;     // [2][1536]
    float* tmpXC_ = pb + 6144;     // [2][1536]
    float* qb_    = pb + 9216;     // [2][512]
    float* e_     = pb + 10240;    // [2][64][8]
    float* ctx0_  = pb + 11264;    // [2][1024]
    float* ctx_   = pb + 13312;    // [2][1024]
    float* pool_  = pb + 15360;    // [2][1024]
    float* s0_    = pb + 17408;    // [2][512]

    // ---------------- LDS (~62 KB) ----------------
    __shared__ float sal[2][512];    // carry s_t (identical in all 8 WGs)
    __shared__ float sbl[2][512];    // cell-GRU "state"
    __shared__ float al[2][64];      // alpha for head i
    __shared__ float outcl[2][64];   // ctx@Wc slice
    __shared__ float xml[2][64];     // xs_mask rows
    __shared__ float red[8][24];
    __shared__ float red2[24];
    __shared__ float arena[13056];   // staging + combine scratch
    float* xv   = arena;             // [2][1024] staging
    float* comb = arena + 2048;      // combine region (<= 4608 floats)

    unsigned gen = 0;
    auto gbar = [&](){
        __syncthreads();             // vmcnt(0) drain = release for all g_st
        ++gen;
        if (tid == 0){
            __hip_atomic_fetch_add(cntg, 1u, __ATOMIC_RELAXED, __HIP_MEMORY_SCOPE_AGENT);
            while (__hip_atomic_load(cntg, __ATOMIC_RELAXED, __HIP_MEMORY_SCOPE_AGENT) < 8u*gen)
                __builtin_amdgcn_s_sleep(2);
        }
        asm volatile("" ::: "memory");
        __syncthreads();
    };

    auto breduce = [&](float* v, int nv){
        for (int n = 0; n < nv; ++n){
            float x = v[n];
            #pragma unroll
            for (int o = 32; o; o >>= 1) x += __shfl_xor(x, o);
            v[n] = x;
        }
        if (lane == 0) for (int n = 0; n < nv; ++n) red[wv][n] = v[n];
        __syncthreads();
        if (tid < nv){ float s = 0.f; for (int q = 0; q < 8; ++q) s += red[q][tid]; red2[tid] = s; }
        __syncthreads();
        for (int n = 0; n < nv; ++n) v[n] = red2[n];
    };

    // dual-matrix sliced GEMV for 2 batch rows, 256 output cols, K-split 8.
    // cg<CGA -> Wa (cols ca+4cg), else Wb (cols cb+4(cg-CGA)). Returns value for
    // (bb=tid>>8, c=tid&255). float4 weight loads, 8-deep batches.
    auto gemv2 = [&](const float* Wa, int lda, int ca,
                     const float* Wb, int ldb, int cb, int CGA,
                     const float* x0, const float* x1, int K)->float{
        int cg = tid & 63, kq = tid >> 6;
        const float* W; int ld, col;
        if (cg < CGA){ W = Wa; ld = lda; col = ca + 4*cg; }
        else         { W = Wb; ld = ldb; col = cb + 4*(cg - CGA); }
        int Kq = K >> 3;
        const float* wp = W + (size_t)(kq*Kq)*ld + col;
        const float* xa = x0 + kq*Kq;
        const float* xb = x1 + kq*Kq;
        float a0=0,a1=0,a2=0,a3=0, c0=0,c1=0,c2=0,c3=0;
        for (int kk = 0; kk < Kq; kk += 8){
            float4 wr[8];
            #pragma unroll
            for (int u = 0; u < 8; ++u) wr[u] = *(const float4*)(wp + (size_t)(kk+u)*ld);
            #pragma unroll
            for (int u = 0; u < 8; ++u){
                float xA = xa[kk+u], xB = xb[kk+u];
                a0 = fmaf(xA, wr[u].x, a0); a1 = fmaf(xA, wr[u].y, a1);
                a2 = fmaf(xA, wr[u].z, a2); a3 = fmaf(xA, wr[u].w, a3);
                c0 = fmaf(xB, wr[u].x, c0); c1 = fmaf(xB, wr[u].y, c1);
                c2 = fmaf(xB, wr[u].z, c2); c3 = fmaf(xB, wr[u].w, c3);
            }
        }
        float* cp = comb + tid*9;
        cp[0]=a0; cp[1]=a1; cp[2]=a2; cp[3]=a3;
        cp[4]=c0; cp[5]=c1; cp[6]=c2; cp[7]=c3;
        __syncthreads();
        int bb = tid >> 8, c = tid & 255, cgq = c >> 2, j = c & 3;
        float s = 0.f;
        #pragma unroll
        for (int q = 0; q < 8; ++q) s += comb[(q*64 + cgq)*9 + bb*4 + j];
        __syncthreads();
        return s;
    };

    // ======================= precompute =======================
    if (tid < 128) xml[tid>>6][tid&63] = xs_mask[(size_t)(b0 + (tid>>6))*64 + (tid&63)];
    __syncthreads();

    // ---- uh (private): 16 jobs (2b x 8 l), 512 cols, K=1024; W_keys read once ----
    {
        int c4 = tid & 127, kq = tid >> 7;           // 4 kq x 256 k
        unsigned base[16];
        #pragma unroll
        for (int j = 0; j < 16; ++j){
            int bb = j >> 3, l = i*8 + (j & 7);
            base[j] = (unsigned)(((b0+bb)*64 + l)*1024 + kq*256);
        }
        const float* wp = W_keys + (size_t)(kq*256)*512 + 4*c4;
        float4 acc[16];
        #pragma unroll
        for (int j = 0; j < 16; ++j) acc[j] = make_float4(0.f,0.f,0.f,0.f);
        for (int kk = 0; kk < 256; ++kk){
            float4 wr = *(const float4*)(wp + (size_t)kk*512);
            #pragma unroll
            for (int j = 0; j < 16; ++j){
                float xr = xs_h[base[j] + kk];
                acc[j].x = fmaf(xr, wr.x, acc[j].x); acc[j].y = fmaf(xr, wr.y, acc[j].y);
                acc[j].z = fmaf(xr, wr.z, acc[j].z); acc[j].w = fmaf(xr, wr.w, acc[j].w);
            }
        }
        for (int r = 0; r < 16; ++r){
            float* cp = arena + tid*5;
            cp[0]=acc[r].x; cp[1]=acc[r].y; cp[2]=acc[r].z; cp[3]=acc[r].w;
            __syncthreads();
            int c = tid; float s = 0.f;
            #pragma unroll
            for (int q = 0; q < 4; ++q) s += arena[(q*128 + (c>>2))*5 + (c&3)];
            uhP[((size_t)w*16 + r)*512 + c] = s;
            __syncthreads();
        }
    }

    // ---- AXn (published to group): 16 rows (2b x 8 t), LN(ys_e@Wx_cell)*gx+bx ----
    // LN variance is TWO-PASS (mu first, then mean((v-mu)^2)) to match reference
    // numerics; the one-pass E[x^2]-mu^2 form cancels catastrophically in fp32.
    for (int g = 0; g < 3; ++g){
        int c4 = tid & 127, kq = tid >> 7;           // 4 kq x 128 k
        unsigned base[16];
        #pragma unroll
        for (int j = 0; j < 16; ++j){
            int bb = j >> 3, t = i*8 + (j & 7);
            base[j] = (unsigned)(((b0+bb)*64 + t)*512 + kq*128);
        }
        const float* wp = Wx_cell + (size_t)(kq*128)*1536 + g*512 + 4*c4;
        float4 acc[16];
        #pragma unroll
        for (int j = 0; j < 16; ++j) acc[j] = make_float4(0.f,0.f,0.f,0.f);
        for (int kk = 0; kk < 128; ++kk){
            float4 wr = *(const float4*)(wp + (size_t)kk*1536);
            #pragma unroll
            for (int j = 0; j < 16; ++j){
                float xr = ys_e[base[j] + kk];
                acc[j].x = fmaf(xr, wr.x, acc[j].x); acc[j].y = fmaf(xr, wr.y, acc[j].y);
                acc[j].z = fmaf(xr, wr.z, acc[j].z); acc[j].w = fmaf(xr, wr.w, acc[j].w);
            }
        }
        for (int r = 0; r < 16; ++r){
            float* cp = arena + tid*5;
            cp[0]=acc[r].x; cp[1]=acc[r].y; cp[2]=acc[r].z; cp[3]=acc[r].w;
            __syncthreads();
            int c = tid; float val = 0.f;
            #pragma unroll
            for (int q = 0; q < 4; ++q) val += arena[(q*128 + (c>>2))*5 + (c&3)];
            float s1[1] = { val };
            breduce(s1, 1);
            float mu = s1[0]*(1.f/512.f);
            float d = val - mu;
            float s2[1] = { d*d };
            breduce(s2, 1);
            float rstd = rsqrtf(s2[0]*(1.f/512.f) + 1e-5f);
            int bb = r >> 3, t = i*8 + (r & 7), cg2 = g*512 + c;
            g_st(&AXn[(((size_t)(b0+bb))*64 + t)*1536 + cg2],
                 d*rstd*gx_cell[cg2] + bx_cell[cg2]);
            __syncthreads();
        }
    }

    // ---- YWb (private): 128 rows (2b x 64 t) in 8 chunks, 64-col slice ----
    for (int cc = 0; cc < 8; ++cc){
        int c4 = tid & 15, kq = tid >> 4;            // 32 kq x 16 k
        unsigned base[16];
        #pragma unroll
        for (int r = 0; r < 16; ++r){
            int rg = cc*16 + r, bb = rg >> 6, t = rg & 63;
            base[r] = (unsigned)(((b0+bb)*64 + t)*512 + kq*16);
        }
        const float* wp = Wy + (size_t)(kq*16)*512 + i*64 + 4*c4;
        float4 acc[16];
        #pragma unroll
        for (int r = 0; r < 16; ++r) acc[r] = make_float4(0.f,0.f,0.f,0.f);
        for (int kk = 0; kk < 16; ++kk){
            float4 wr = *(const float4*)(wp + (size_t)kk*512);
            #pragma unroll
            for (int r = 0; r < 16; ++r){
                float xr = ys_e[base[r] + kk];
                acc[r].x = fmaf(xr, wr.x, acc[r].x); acc[r].y = fmaf(xr, wr.y, acc[r].y);
                acc[r].z = fmaf(xr, wr.z, acc[r].z); acc[r].w = fmaf(xr, wr.w, acc[r].w);
            }
        }
        for (int r = 0; r < 16; ++r){
            float* cp = arena + tid*5;
            cp[0]=acc[r].x; cp[1]=acc[r].y; cp[2]=acc[r].z; cp[3]=acc[r].w;
            __syncthreads();
            if (tid < 64){
                int c = tid; float s = 0.f;
                #pragma unroll
                for (int q = 0; q < 32; ++q) s += arena[(q*16 + (c>>2))*5 + (c&3)];
                int rg = cc*16 + r, bb = rg >> 6, t = rg & 63;
                YWbP[(((size_t)w*2 + bb)*64 + t)*64 + c] = s + by[i*64 + c];
            }
            __syncthreads();
        }
    }

    // ---- pooled slice ----
    if (tid < 256){
        int bb = tid >> 7, c = i*128 + (tid & 127);
        float msum = 0.f;
        for (int l = 0; l < 64; ++l) msum += xml[bb][l];
        float a = 0.f;
        for (int l = 0; l < 64; ++l)
            a += xs_h[((size_t)(b0+bb)*64 + l)*1024 + c] * xml[bb][l];
        g_st(&pool_[bb*1024 + c], a / msum);
    }
    gbar();   // publish AXn + pooled (group-local; no global barrier needed)

    // ---- s0 = tanh(pooled @ W_sinit + b) ----
    for (int k = tid; k < 2048; k += TPB) xv[k] = g_ld(&pool_[k]);
    __syncthreads();
    {
        int c4 = tid & 15, kq = tid >> 4;            // 32 kq x 32 k
        const float* wp = W_sinit + (size_t)(kq*32)*512 + i*64 + 4*c4;
        float4 A = make_float4(0.f,0.f,0.f,0.f), Bv = make_float4(0.f,0.f,0.f,0.f);
        for (int kk = 0; kk < 32; ++kk){
            float4 wr = *(const float4*)(wp + (size_t)kk*512);
            float xA = xv[kq*32 + kk], xB = xv[1024 + kq*32 + kk];
            A.x = fmaf(xA, wr.x, A.x); A.y = fmaf(xA, wr.y, A.y);
            A.z = fmaf(xA, wr.z, A.z); A.w = fmaf(xA, wr.w, A.w);
            Bv.x = fmaf(xB, wr.x, Bv.x); Bv.y = fmaf(xB, wr.y, Bv.y);
            Bv.z = fmaf(xB, wr.z, Bv.z); Bv.w = fmaf(xB, wr.w, Bv.w);
        }
        float* cp = comb + tid*9;
        cp[0]=A.x; cp[1]=A.y; cp[2]=A.z; cp[3]=A.w;
        cp[4]=Bv.x; cp[5]=Bv.y; cp[6]=Bv.z; cp[7]=Bv.w;
        __syncthreads();
        if (tid < 128){
            int bb = tid >> 6, c = tid & 63; float s = 0.f;
            #pragma unroll
            for (int q = 0; q < 32; ++q) s += comb[(q*16 + (c>>2))*9 + bb*4 + (c&3)];
            g_st(&s0_[bb*512 + i*64 + c], tanhf(s + b_sinit[i*64 + c]));
        }
        __syncthreads();
    }
    gbar();
    sal[0][tid] = g_ld(&s0_[tid]);
    sal[1][tid] = g_ld(&s0_[512 + tid]);
    __syncthreads();

    // ---- tmpH for t=0 ----
    {
        float r0 = gemv2(Wsm, 512, i*64, Wh_cell, 1536, i*192, 16,
                         &sal[0][0], &sal[1][0], 512);
        int bb = tid >> 8, c = tid & 255;
        if (c >= 64) g_st(&tmpH_[bb*1536 + i*192 + (c - 64)], r0);
    }
    gbar();

    // ======================= sequential scan =======================
    for (int t = 0; t < 64; ++t){
        float ymr[2] = { ys_mask[(size_t)b0*64 + t], ys_mask[(size_t)(b0+1)*64 + t] };

        // ---- phase A: cell-GRU (redundant, two-pass LN) + qb/tmpHC slice ----
        {
            float th[2][3], ax[2][3], st[6];
            #pragma unroll
            for (int bb = 0; bb < 2; ++bb)
                #pragma unroll
                for (int g = 0; g < 3; ++g){
                    th[bb][g] = g_ld(&tmpH_[bb*1536 + g*512 + tid]);
                    ax[bb][g] = g_ld(&AXn[(((size_t)(b0+bb))*64 + t)*1536 + g*512 + tid]);
                    st[bb*3+g] = th[bb][g];
                }
            breduce(st, 6);
            float dv[2][3], st2[6];
            #pragma unroll
            for (int bb = 0; bb < 2; ++bb)
                #pragma unroll
                for (int g = 0; g < 3; ++g){
                    float mu = st[bb*3+g]*(1.f/512.f);
                    dv[bb][g] = th[bb][g] - mu;
                    st2[bb*3+g] = dv[bb][g]*dv[bb][g];
                }
            breduce(st2, 6);
            #pragma unroll
            for (int bb = 0; bb < 2; ++bb){
                float ah[3];
                #pragma unroll
                for (int g = 0; g < 3; ++g){
                    float var = st2[bb*3+g]*(1.f/512.f);
                    ah[g] = dv[bb][g]*rsqrtf(var + 1e-5f)*gh_cell[g*512 + tid];
                }
                float h  = sal[bb][tid];
                float r  = sigm(ax[bb][0] + ah[0]);
                float z  = sigm(ax[bb][1] + ah[1]);
                float hc = tanhf(ax[bb][2] + r*ah[2]);
                float hn = (1.f - z)*h + z*hc;
                sbl[bb][tid] = ymr[bb]*hn + (1.f - ymr[bb])*h;
            }
        }
        __syncthreads();
        {
            float ra = gemv2(Wq, 512, i*64, Wh_cond, 1536, i*192, 16,
                             &sbl[0][0], &sbl[1][0], 512);
            int bb = tid >> 8, c = tid & 255;
            if (c < 64){ int col = i*64 + c; g_st(&qb_[bb*512 + col], ra + bq[col]); }
            else g_st(&tmpHC_[bb*1536 + i*192 + (c - 64)], ra);
        }
        gbar();  // A

        // ---- phase B: attention scores for my 16 (b,l) jobs ----
        for (int k = tid; k < 1024; k += TPB) xv[k] = g_ld(&qb_[k]);
        __syncthreads();
        for (int jj = wv; jj < 16; jj += 8){
            int bb = jj >> 3, l = i*8 + (jj & 7);
            float acc[8] = {0.f,0.f,0.f,0.f,0.f,0.f,0.f,0.f};
            #pragma unroll
            for (int u = 0; u < 8; ++u){
                int d = u*64 + lane;
                float hid = tanhf(uhP[((size_t)w*16 + jj)*512 + d] + xv[bb*512 + d]);
                float4 va = *(const float4*)&V_att[(size_t)d*8];
                float4 vb = *(const float4*)&V_att[(size_t)d*8 + 4];
                acc[0] = fmaf(hid, va.x, acc[0]); acc[1] = fmaf(hid, va.y, acc[1]);
                acc[2] = fmaf(hid, va.z, acc[2]); acc[3] = fmaf(hid, va.w, acc[3]);
                acc[4] = fmaf(hid, vb.x, acc[4]); acc[5] = fmaf(hid, vb.y, acc[5]);
                acc[6] = fmaf(hid, vb.z, acc[6]); acc[7] = fmaf(hid, vb.w, acc[7]);
            }
            #pragma unroll
            for (int h = 0; h < 8; ++h)
                #pragma unroll
                for (int o = 32; o; o >>= 1) acc[h] += __shfl_xor(acc[h], o);
            if (lane == 0){
                float mk = xml[bb][l];
                #pragma unroll
                for (int h = 0; h < 8; ++h)
                    g_st(&e_[((size_t)bb*64 + l)*8 + h], (mk > 0.f) ? acc[h] : -1e9f);
            }
        }
        gbar();  // B

        // ---- phase C: softmax (head i) + ctx0 slice ----
        if (wv < 2){
            int bb = wv;
            float v = g_ld(&e_[((size_t)bb*64 + lane)*8 + i]);
            float mx = v;
            #pragma unroll
            for (int o = 32; o; o >>= 1) mx = fmaxf(mx, __shfl_xor(mx, o));
            float ex = expf(v - mx);
            float ss = ex;
            #pragma unroll
            for (int o = 32; o; o >>= 1) ss += __shfl_xor(ss, o);
            al[bb][lane] = ex / ss;
        }
        __syncthreads();
        {
            int kq = tid >> 6, job = tid & 63, bb = job >> 5, cg = job & 31;
            int c0 = i*128 + 4*cg;
            float4 a4 = make_float4(0.f,0.f,0.f,0.f);
            #pragma unroll
            for (int u = 0; u < 8; ++u){
                int l = kq*8 + u;
                float a = al[bb][l];
                float4 xw = *(const float4*)&xs_h[((size_t)(b0+bb)*64 + l)*1024 + c0];
                a4.x = fmaf(a, xw.x, a4.x); a4.y = fmaf(a, xw.y, a4.y);
                a4.z = fmaf(a, xw.z, a4.z); a4.w = fmaf(a, xw.w, a4.w);
            }
            float* cp = comb + tid*5;
            cp[0]=a4.x; cp[1]=a4.y; cp[2]=a4.z; cp[3]=a4.w;
            __syncthreads();
            if (tid < 256){
                int bb2 = tid >> 7, c = tid & 127; float s = 0.f;
                #pragma unroll
                for (int q = 0; q < 8; ++q) s += comb[(q*64 + bb2*32 + (c>>2))*5 + (c&3)];
                g_st(&ctx0_[bb2*1024 + i*128 + c], s);
            }
            __syncthreads();
        }
        gbar();  // C

        // ---- phase D: ctx = (ctx0 @ Wo + bo) * ym  (direct Wo, K-split 16) ----
        for (int k = tid; k < 2048; k += TPB) xv[k] = g_ld(&ctx0_[k]);
        __syncthreads();
        {
            int kq = tid >> 5, cg = tid & 31;        // 16 kq x 64 k, 32 cg x 4 cols
            int c0 = i*128 + 4*cg;
            const float* wp = Wo + (size_t)(kq*64)*1024 + c0;
            const float* xa = xv + kq*64;
            const float* xb = xv + 1024 + kq*64;
            float a0=0,a1=0,a2=0,a3=0, d0=0,d1=0,d2=0,d3=0;
            for (int kk = 0; kk < 64; kk += 8){
                float4 wr[8];
                #pragma unroll
                for (int u = 0; u < 8; ++u) wr[u] = *(const float4*)(wp + (size_t)(kk+u)*1024);
                #pragma unroll
                for (int u = 0; u < 8; ++u){
                    float xA = xa[kk+u], xB = xb[kk+u];
                    a0 = fmaf(xA, wr[u].x, a0); a1 = fmaf(xA, wr[u].y, a1);
                    a2 = fmaf(xA, wr[u].z, a2); a3 = fmaf(xA, wr[u].w, a3);
                    d0 = fmaf(xB, wr[u].x, d0); d1 = fmaf(xB, wr[u].y, d1);
                    d2 = fmaf(xB, wr[u].z, d2); d3 = fmaf(xB, wr[u].w, d3);
                }
            }
            float* cp = comb + tid*9;
            cp[0]=a0; cp[1]=a1; cp[2]=a2; cp[3]=a3;
            cp[4]=d0; cp[5]=d1; cp[6]=d2; cp[7]=d3;
            __syncthreads();
            if (tid < 256){
                int bb2 = tid >> 7, c = tid & 127; float s = 0.f;
                #pragma unroll
                for (int q = 0; q < 16; ++q) s += comb[(q*32 + (c>>2))*9 + bb2*4 + (c&3)];
                float ym2 = bb2 ? ymr[1] : ymr[0];
                g_st(&ctx_[bb2*1024 + i*128 + c], (s + bo[i*128 + c]) * ym2);
            }
            __syncthreads();
        }
        gbar();  // D

        // ---- phase E: tmpXC (Wx_cond) + outc (Wc) from ctx ----
        for (int k = tid; k < 2048; k += TPB) xv[k] = g_ld(&ctx_[k]);
        __syncthreads();
        {
            float re = gemv2(Wx_cond, 1536, i*192, Wc, 512, i*64, 48,
                             &xv[0], &xv[1024], 1024);
            int bb = tid >> 8, c = tid & 255;
            if (c < 192){
                g_st(&tmpXC_[bb*1536 + i*192 + c], re);
            } else {
                outcl[bb][c - 192] = re;
            }
        }
        gbar();  // E

        // ---- phase F: cond-GRU (redundant, two-pass LN) + out + tmpH(t+1) ----
        {
            float tx[2][3], th[2][3], st[12];
            #pragma unroll
            for (int bb = 0; bb < 2; ++bb)
                #pragma unroll
                for (int g = 0; g < 3; ++g){
                    tx[bb][g] = g_ld(&tmpXC_[bb*1536 + g*512 + tid]);
                    th[bb][g] = g_ld(&tmpHC_[bb*1536 + g*512 + tid]);
                    st[bb*3+g]     = tx[bb][g];
                    st[6 + bb*3+g] = th[bb][g];
                }
            breduce(st, 12);
            float dx[2][3], dh[2][3], st2[12];
            #pragma unroll
            for (int bb = 0; bb < 2; ++bb)
                #pragma unroll
                for (int g = 0; g < 3; ++g){
                    float mux = st[bb*3+g]*(1.f/512.f);
                    float muh = st[6 + bb*3+g]*(1.f/512.f);
                    dx[bb][g] = tx[bb][g] - mux;
                    dh[bb][g] = th[bb][g] - muh;
                    st2[bb*3+g]     = dx[bb][g]*dx[bb][g];
                    st2[6 + bb*3+g] = dh[bb][g]*dh[bb][g];
                }
            breduce(st2, 12);
            float snew[2];
            #pragma unroll
            for (int bb = 0; bb < 2; ++bb){
                float axc[3], ahc[3];
                #pragma unroll
                for (int g = 0; g < 3; ++g){
                    int c2 = g*512 + tid;
                    float vax = st2[bb*3+g]*(1.f/512.f);
                    float vah = st2[6 + bb*3+g]*(1.f/512.f);
                    axc[g] = dx[bb][g]*rsqrtf(vax + 1e-5f)*gx_cond[c2] + bx_cond[c2];
                    ahc[g] = dh[bb][g]*rsqrtf(vah + 1e-5f)*gh_cond[c2];
                }
                float h  = sbl[bb][tid];
                float r  = sigm(axc[0] + ahc[0]);
                float z  = sigm(axc[1] + ahc[1]);
                float hc = tanhf(axc[2] + r*ahc[2]);
                float hn = (1.f - z)*h + z*hc;
                snew[bb] = ymr[bb]*hn + (1.f - ymr[bb])*h;
            }
            sal[0][tid] = snew[0];
            sal[1][tid] = snew[1];
        }
        __syncthreads();
        {
            float rf = gemv2(Wsm, 512, i*64, Wh_cell, 1536, i*192, 16,
                             &sal[0][0], &sal[1][0], 512);
            int bb = tid >> 8, c = tid & 255;
            if (c < 64){
                int col = i*64 + c;
                float ymf = bb ? ymr[1] : ymr[0];
                float v = rf + YWbP[(((size_t)w*2 + bb)*64 + t)*64 + c]
                        + outcl[bb][c] + bc[col] + bs[col];
                out[(((size_t)(b0+bb))*64 + t)*512 + col] = tanhf(v)*ymf;
            } else {
                g_st(&tmpH_[bb*1536 + i*192 + (c - 64)], rf);
            }
        }
        gbar();  // F
    }
}

// ---------------------------------------------------------------------------
extern "C" void kernel_launch(void* const* d_in, const int* in_sizes, int n_in,
                              void* d_out, int out_size, void* d_ws, size_t ws_size,
                              hipStream_t stream)
{
    // re-zero barrier counters on every graph replay
    hipMemsetAsync(d_ws, 0, 4096, stream);

    decoder_persistent<<<dim3(NWG), dim3(TPB), 0, stream>>>(
        (const float*)d_in[0],  (const float*)d_in[1],  (const float*)d_in[2],
        (const float*)d_in[3],  (const float*)d_in[4],  (const float*)d_in[5],
        (const float*)d_in[6],  (const float*)d_in[7],  (const float*)d_in[8],
        (const float*)d_in[9],  (const float*)d_in[10], (const float*)d_in[11],
        (const float*)d_in[12], (const float*)d_in[13], (const float*)d_in[14],
        (const float*)d_in[15], (const float*)d_in[16], (const float*)d_in[17],
        (const float*)d_in[18], (const float*)d_in[19], (const float*)d_in[20],
        (const float*)d_in[21], (const float*)d_in[22], (const float*)d_in[23],
        (const float*)d_in[24], (const float*)d_in[25], (const float*)d_in[26],
        (const float*)d_in[27],
        (float*)d_out, (float*)d_ws);
}